// Round 8
// baseline (2021.255 us; speedup 1.0000x reference)
//
#include <hip/hip_runtime.h>
#include <hip/hip_bf16.h>

#define B   128
#define NA  8
#define AD  16
#define DM  512
#define DI  1024
#define DS  32
#define DC  4
#define DR  32
#define NB  4
#define OD  128

typedef unsigned int uint32;
typedef _Float16 h2f __attribute__((ext_vector_type(2)));

__device__ __forceinline__ float sigmoidf_(float x){ return 1.0f/(1.0f+__expf(-x)); }
__device__ __forceinline__ float softplusf_(float x){ return fmaxf(x,0.0f)+log1pf(__expf(-fabsf(x))); }

// f16 pair helpers: one uint32 = half2 (lo = first, hi = second)
__device__ __forceinline__ float dot2h(uint32 a, uint32 b, float c){
    union { uint32 u; h2f h; } ua, ub;
    ua.u = a; ub.u = b;
#if __has_builtin(__builtin_amdgcn_fdot2)
    return __builtin_amdgcn_fdot2(ua.h, ub.h, c, false);
#else
    return c + (float)ua.h.x*(float)ub.h.x + (float)ua.h.y*(float)ub.h.y;
#endif
}
__device__ __forceinline__ uint32 packh2(float a, float b){
    union { uint32 u; h2f h; } w;
    w.h.x = (_Float16)a; w.h.y = (_Float16)b;
    return w.u;
}
__device__ __forceinline__ float loh(uint32 u){
    union { uint32 uu; h2f h; } w; w.uu = u; return (float)w.h.x;
}
__device__ __forceinline__ float hih(uint32 u){
    union { uint32 uu; h2f h; } w; w.uu = u; return (float)w.h.y;
}

// ---------------- init / conversion kernels ----------------

__global__ __launch_bounds__(256) void k_ctx(const float* __restrict__ obs_rep,
    const float* __restrict__ obs, const float* __restrict__ Wobs,
    float* __restrict__ ctx)
{
    int ib = blockIdx.x;          // < B*8
    int b = ib >> 3, i = ib & 7;
    __shared__ float orow[OD];
    int tid = threadIdx.x;
    if (tid < OD) orow[tid] = obs[(size_t)(b*NA+i)*OD + tid];
    __syncthreads();
    for (int m = tid; m < DM; m += 256){
        float acc = obs_rep[(size_t)(b*NA+i)*DM + m];
        for (int o = 0; o < OD; o++)
            acc += orow[o]*Wobs[o*DM + m];
        ctx[(size_t)(i*B + b)*DM + m] = acc;
    }
}

// merged converter: W1H | WoH | WxH | WdtH | negA | pP/xb0  (index-ranged)
__global__ __launch_bounds__(256) void k_setup(
    const float* __restrict__ W1s, const float* __restrict__ W1c,
    const float* __restrict__ Wos, const float* __restrict__ Woc,
    const float* __restrict__ Wxs, const float* __restrict__ Wxc,
    const float* __restrict__ Wds, const float* __restrict__ Wdc,
    const float* __restrict__ Als, const float* __restrict__ Alc,
    const float* __restrict__ bemb,
    uint32* __restrict__ W1H, uint32* __restrict__ WoH,
    uint32* __restrict__ WxH, uint32* __restrict__ WdtH,
    float* __restrict__ negA, float* __restrict__ xb0, float* __restrict__ pP)
{
    int idx = blockIdx.x*256 + threadIdx.x;
    if (idx < 4194304){   // W1H [8][256][2048]
        int bs = idx >> 19, rr = idx & 524287;
        int k2 = rr >> 11, c = rr & 2047;
        int nb = bs >> 1, st = bs & 1;
        const float* src = (st ? W1c : W1s) + (size_t)nb*1048576 + (size_t)(2*k2)*2048 + c;
        W1H[idx] = packh2(src[0], src[2048]);
        return;
    }
    idx -= 4194304;
    if (idx < 2097152){   // WoH [8][512][512]
        int bs = idx >> 18, rr = idx & 262143;
        int k2 = rr >> 9, c = rr & 511;
        int nb = bs >> 1, st = bs & 1;
        const float* src = (st ? Woc : Wos) + (size_t)nb*DI*DM + (size_t)(2*k2)*DM + c;
        WoH[idx] = packh2(src[0], src[DM]);
        return;
    }
    idx -= 2097152;
    if (idx < 393216){    // WxH [8][96][512]
        int bs = idx / 49152, rr = idx % 49152;
        int j = rr >> 9, k2 = rr & 511;
        int nb = bs >> 1, st = bs & 1;
        const float* src = (st ? Wxc : Wxs) + (size_t)nb*DI*96 + (size_t)(2*k2)*96 + j;
        WxH[idx] = packh2(src[0], src[96]);
        return;
    }
    idx -= 393216;
    if (idx < 131072){    // WdtH [8][16][1024]
        int bs = idx >> 14, rr = idx & 16383;
        int r2 = rr >> 10, d = rr & 1023;
        int nb = bs >> 1, st = bs & 1;
        const float* src = (st ? Wdc : Wds) + (size_t)nb*DR*DI + (size_t)(2*r2)*DI + d;
        WdtH[idx] = packh2(src[0], src[DI]);
        return;
    }
    idx -= 131072;
    if (idx < 262144){    // negA
        int bs = idx >> 15, rr = idx & 32767;
        int nb = bs >> 1, st = bs & 1;
        const float* src = (st ? Alc : Als) + (size_t)nb*DI*DS + rr;
        negA[idx] = -__expf(*src);
        return;
    }
    idx -= 262144;
    // idx < 524288: pP zero; first 65536 also xb0 init
    pP[idx] = 0.f;
    if (idx < B*DM) xb0[idx] = bemb[idx & (DM-1)];
}

// ---------------- per-step kernels ----------------

struct SP {
    const uint32 *W1H, *WoH, *WxH, *WdtH;
    const float *negA, *ctxG;
    const float *cw_s, *cb_s, *dtb_s, *D_s;
    const float *cw_c, *cb_c, *dtb_c, *D_c;
    const float *ln1, *ln2;
    float *xcG, *szG, *xpP, *pP;
    uint32 *convrU, *hG;
};

// grid 256 = 32 rowgroups (R=4 rows) x 8 colgroups, 1024 threads.
// gemm1 weights prefetched into registers at kernel entry (addresses depend
// only on blockIdx/bs) so cold-L2 latency hides under fold+LN.
__global__ __launch_bounds__(1024) void k_step1(SP P, const float* __restrict__ xin,
    float* __restrict__ xout, int i, int bs)
{
    int rg = blockIdx.x >> 3, cg = blockIdx.x & 7;
    int t = threadIdx.x;
    int st = bs & 1, nb = bs >> 1;
    const float* lns = (st ? P.ln2 : P.ln1) + (size_t)nb*DM;
    const float* cw  = (st ? P.cw_c : P.cw_s) + (size_t)nb*DC*DI;
    const float* cb  = (st ? P.cb_c : P.cb_s) + (size_t)nb*DI;

    __shared__ uint32 ulnP[4][256];
    __shared__ float red1[16][4][256];   // 64 KB
    __shared__ float xzL[4][256];
    __shared__ uint32 xcP[4][128];
    __shared__ float xpt[2][4][96];
    __shared__ float wred[4][2][2];
    __shared__ float ms2[4][2];

    // ---- prefetch gemm1 weight slice into registers ----
    int cp = t & 63, kg = t >> 6;
    uint4 wreg[16];
    {
        const uint32* w1 = P.W1H + ((size_t)bs << 19);     // [256 k2][2048 c]
        const uint4* wp = (const uint4*)(w1 + ((size_t)(kg*16) << 11)) + (cg*64 + cp);
        #pragma unroll
        for (int k2i = 0; k2i < 16; k2i++) wreg[k2i] = wp[(size_t)k2i << 9];
    }

    // ---- fold x + sum(pP) (t<512: row r of 4, 4 consecutive cols) ----
    int r = (t >> 7) & 3, cq = t & 127;
    float4 v4 = make_float4(0.f,0.f,0.f,0.f);
    if (t < 512){
        int row = rg*4 + r;
        v4 = *(const float4*)&xin[(size_t)row*DM + cq*4];
        #pragma unroll
        for (int gg = 0; gg < 8; gg++){
            float4 q4 = *(const float4*)&P.pP[((size_t)gg*B + row)*DM + cq*4];
            v4.x += q4.x; v4.y += q4.y; v4.z += q4.z; v4.w += q4.w;
        }
        if (cg == 0) *(float4*)&xout[(size_t)row*DM + cq*4] = v4;
        float sv = v4.x+v4.y+v4.z+v4.w;
        float qv = v4.x*v4.x+v4.y*v4.y+v4.z*v4.z+v4.w*v4.w;
        #pragma unroll
        for (int off = 32; off > 0; off >>= 1){
            sv += __shfl_down(sv, off);
            qv += __shfl_down(qv, off);
        }
        int lane = t & 63, wid = t >> 6;
        if (lane == 0){ wred[wid>>1][wid&1][0] = sv; wred[wid>>1][wid&1][1] = qv; }
    }
    __syncthreads();
    if (t < 4){
        float S = wred[t][0][0] + wred[t][1][0];
        float Q = wred[t][0][1] + wred[t][1][1];
        float m = S*(1.0f/DM);
        float var = Q*(1.0f/DM) - m*m;
        ms2[t][0] = m; ms2[t][1] = rsqrtf(var + 1e-5f);
    }
    __syncthreads();

    // ---- LN -> packed f16 pairs ----
    if (t < 512){
        int row = rg*4 + r;
        float m = ms2[r][0], rs = ms2[r][1];
        float4 l4 = *(const float4*)&lns[cq*4];
        float u0 = (v4.x - m)*rs*l4.x;
        float u1 = (v4.y - m)*rs*l4.y;
        float u2 = (v4.z - m)*rs*l4.z;
        float u3 = (v4.w - m)*rs*l4.w;
        if (st){
            float4 c4 = *(const float4*)&P.ctxG[((size_t)i*B + row)*DM + cq*4];
            u0 += c4.x; u1 += c4.y; u2 += c4.z; u3 += c4.w;
        }
        ulnP[r][2*cq]   = packh2(u0, u1);
        ulnP[r][2*cq+1] = packh2(u2, u3);
    }
    __syncthreads();

    // ---- gemm1: consume prefetched weights; 4 rows per thread ----
    {
        float a[4][4] = {};
        #pragma unroll
        for (int k2i = 0; k2i < 16; k2i++){
            uint4 q = wreg[k2i];
            int k2 = kg*16 + k2i;
            uint32 u0 = ulnP[0][k2], u1 = ulnP[1][k2];
            uint32 u2 = ulnP[2][k2], u3 = ulnP[3][k2];
            a[0][0]=dot2h(u0,q.x,a[0][0]); a[0][1]=dot2h(u0,q.y,a[0][1]);
            a[0][2]=dot2h(u0,q.z,a[0][2]); a[0][3]=dot2h(u0,q.w,a[0][3]);
            a[1][0]=dot2h(u1,q.x,a[1][0]); a[1][1]=dot2h(u1,q.y,a[1][1]);
            a[1][2]=dot2h(u1,q.z,a[1][2]); a[1][3]=dot2h(u1,q.w,a[1][3]);
            a[2][0]=dot2h(u2,q.x,a[2][0]); a[2][1]=dot2h(u2,q.y,a[2][1]);
            a[2][2]=dot2h(u2,q.z,a[2][2]); a[2][3]=dot2h(u2,q.w,a[2][3]);
            a[3][0]=dot2h(u3,q.x,a[3][0]); a[3][1]=dot2h(u3,q.y,a[3][1]);
            a[3][2]=dot2h(u3,q.z,a[3][2]); a[3][3]=dot2h(u3,q.w,a[3][3]);
        }
        #pragma unroll
        for (int rr = 0; rr < 4; rr++)
            *(float4*)&red1[kg][rr][4*cp] = make_float4(a[rr][0],a[rr][1],a[rr][2],a[rr][3]);
    }
    __syncthreads();
    {
        int r2 = t >> 8, c = t & 255;
        float sacc = red1[0][r2][c];
        #pragma unroll
        for (int gk = 1; gk < 16; gk++) sacc += red1[gk][r2][c];
        xzL[r2][c] = sacc;
    }
    __syncthreads();

    if (cg < 4){
        // ---- conv ring + silu -> xc (t<512) ----
        if (t < 512){
            int r3 = r, pi = cq;
            int row3 = rg*4 + r3;
            int d0 = cg*256 + 2*pi;
            float xz0 = xzL[r3][2*pi], xz1 = xzL[r3][2*pi+1];
            uint32* ring = P.convrU + ((size_t)bs << 18);   // [4][128][512] f16 pairs
            size_t rb = (size_t)row3*512 + (d0>>1);
            ring[((size_t)(i&3))*65536 + rb] = packh2(xz0, xz1);
            float s0 = cb[d0]   + cw[3*DI + d0]  *xz0;
            float s1 = cb[d0+1] + cw[3*DI + d0+1]*xz1;
            if (i >= 1){ uint32 uu = ring[((size_t)((i-1)&3))*65536 + rb];
                s0 += cw[2*DI + d0]*loh(uu); s1 += cw[2*DI + d0+1]*hih(uu); }
            if (i >= 2){ uint32 uu = ring[((size_t)((i-2)&3))*65536 + rb];
                s0 += cw[1*DI + d0]*loh(uu); s1 += cw[1*DI + d0+1]*hih(uu); }
            if (i >= 3){ uint32 uu = ring[((size_t)((i-3)&3))*65536 + rb];
                s0 += cw[0*DI + d0]*loh(uu); s1 += cw[0*DI + d0+1]*hih(uu); }
            float xc0 = s0*sigmoidf_(s0), xc1 = s1*sigmoidf_(s1);
            P.xcG[(size_t)row3*DI + d0]   = xc0;
            P.xcG[(size_t)row3*DI + d0+1] = xc1;
            xcP[r3][pi] = packh2(xc0, xc1);
        }
        __syncthreads();
        // ---- xproj over this 256-k slice: 768 threads x 64-k2 halves ----
        if (t < 768){
            int j = t % 96, q = t / 96;      // q 0..7
            int rx = q & 3, ks = q >> 2;     // ks = k-half
            const uint4* wx = (const uint4*)(P.WxH + (size_t)bs*49152
                              + ((size_t)j << 9) + (cg << 7) + (ks << 6));
            const uint32* xr = &xcP[rx][ks << 6];
            float acc = 0.f;
            #pragma unroll 8
            for (int ii = 0; ii < 16; ii++){
                uint4 q4 = wx[ii];
                acc = dot2h(xr[4*ii+0], q4.x, acc);
                acc = dot2h(xr[4*ii+1], q4.y, acc);
                acc = dot2h(xr[4*ii+2], q4.z, acc);
                acc = dot2h(xr[4*ii+3], q4.w, acc);
            }
            xpt[ks][rx][j] = acc;
        }
        __syncthreads();
        if (t < 384){
            int rx = t/96, j = t - rx*96;
            P.xpP[((size_t)cg*B + rg*4 + rx)*96 + j] = xpt[0][rx][j] + xpt[1][rx][j];
        }
    } else {
        // ---- z path: sz ----
        int r2 = t >> 8, c = t & 255;
        int row2 = rg*4 + r2;
        int d = (cg-4)*256 + c;
        float xz = xzL[r2][c];
        P.szG[(size_t)row2*DI + d] = xz*sigmoidf_(xz);
    }
}

// step2: prefetch gemm2 + dt weights at entry (hidden under rowS fold);
// rowS fold, dt, scan + y, gemm2 -> pP[g]
__global__ __launch_bounds__(1024) void k_step2(SP P, int i, int bs)
{
    int rg = blockIdx.x >> 3, g = blockIdx.x & 7;
    int t = threadIdx.x;
    int st = bs & 1, nb = bs >> 1;
    const float* dtbp = (st ? P.dtb_c : P.dtb_s) + (size_t)nb*DI;
    const float* Dpp  = (st ? P.D_c   : P.D_s  ) + (size_t)nb*DI;
    const int first = (i == 0);

    __shared__ float rowS[4][96];
    __shared__ uint32 rowSP[4][16];
    __shared__ float yzL[4][128];
    __shared__ uint32 yzP[4][64];
    __shared__ float red2[8][4][624];   // padded cols

    // ---- prefetch gemm2 weights (8 uint4) ----
    int cq = t & 127, kg = t >> 7;
    uint4 wor[8];
    {
        const uint32* wo = P.WoH + ((size_t)bs << 18);      // [512 k2][512 c]
        const uint4* wp = (const uint4*)(wo + ((size_t)(g*64 + kg*8) << 9)) + cq;
        #pragma unroll
        for (int k2i = 0; k2i < 8; k2i++) wor[k2i] = wp[(size_t)k2i << 7];
    }
    // ---- prefetch dt weights (t<512) ----
    int r = (t >> 7) & 3, dl = t & 127;
    int d = g*128 + dl;
    uint32 wdtreg[16];
    if (t < 512){
        const uint32* wdt = P.WdtH + ((size_t)bs << 14) + d;   // [16 r2][1024 d]
        #pragma unroll
        for (int r2 = 0; r2 < 16; r2++) wdtreg[r2] = wdt[(size_t)r2 << 10];
    }

    if (t < 384){
        int rx = t/96, j = t - rx*96;
        int row0 = rg*4 + rx;
        size_t base = (size_t)row0*96 + j;
        rowS[rx][j] = P.xpP[base] + P.xpP[(size_t)B*96 + base]
                    + P.xpP[(size_t)2*B*96 + base] + P.xpP[(size_t)3*B*96 + base];
    }
    __syncthreads();
    if (t < 64){
        int rx = t >> 4, q = t & 15;
        rowSP[rx][q] = packh2(rowS[rx][2*q], rowS[rx][2*q+1]);
    }
    __syncthreads();

    if (t < 512){
        int row = rg*4 + r;
        float dp = dtbp[d];
        #pragma unroll
        for (int r2 = 0; r2 < 16; r2++)
            dp = dot2h(rowSP[r][r2], wdtreg[r2], dp);
        float delta = softplusf_(dp);
        float xcv = P.xcG[(size_t)row*DI + d];
        float dxc = delta*xcv;
        const float4* nap = (const float4*)(P.negA + ((size_t)bs << 15) + (size_t)d*DS);
        uint4* hb = ((uint4*)P.hG) + ((size_t)(bs*B + row) << 12) + d;  // [qq][1024]
        float y = 0.f;
        #pragma unroll
        for (int qq = 0; qq < 4; qq++){
            uint4 hu = first ? make_uint4(0u,0u,0u,0u) : hb[qq << 10];
            float4 na0 = nap[2*qq], na1 = nap[2*qq+1];
            int s0 = 8*qq;
            float h0 = loh(hu.x), h1 = hih(hu.x);
            float h2 = loh(hu.y), h3 = hih(hu.y);
            float h4 = loh(hu.z), h5 = hih(hu.z);
            float h6 = loh(hu.w), h7 = hih(hu.w);
            h0 = __expf(delta*na0.x)*h0 + dxc*rowS[r][DR+s0+0];
            h1 = __expf(delta*na0.y)*h1 + dxc*rowS[r][DR+s0+1];
            h2 = __expf(delta*na0.z)*h2 + dxc*rowS[r][DR+s0+2];
            h3 = __expf(delta*na0.w)*h3 + dxc*rowS[r][DR+s0+3];
            h4 = __expf(delta*na1.x)*h4 + dxc*rowS[r][DR+s0+4];
            h5 = __expf(delta*na1.y)*h5 + dxc*rowS[r][DR+s0+5];
            h6 = __expf(delta*na1.z)*h6 + dxc*rowS[r][DR+s0+6];
            h7 = __expf(delta*na1.w)*h7 + dxc*rowS[r][DR+s0+7];
            y += h0*rowS[r][DR+DS+s0+0] + h1*rowS[r][DR+DS+s0+1]
               + h2*rowS[r][DR+DS+s0+2] + h3*rowS[r][DR+DS+s0+3]
               + h4*rowS[r][DR+DS+s0+4] + h5*rowS[r][DR+DS+s0+5]
               + h6*rowS[r][DR+DS+s0+6] + h7*rowS[r][DR+DS+s0+7];
            hu.x = packh2(h0,h1); hu.y = packh2(h2,h3);
            hu.z = packh2(h4,h5); hu.w = packh2(h6,h7);
            hb[qq << 10] = hu;
        }
        y += Dpp[d]*xcv;
        yzL[r][dl] = y*P.szG[(size_t)row*DI + d];
    }
    __syncthreads();
    if (t < 256){
        int rr = t >> 6, k2 = t & 63;
        yzP[rr][k2] = packh2(yzL[rr][2*k2], yzL[rr][2*k2+1]);
    }
    __syncthreads();

    // gemm2: consume prefetched weights; 4 rows per thread
    {
        float a[4][4] = {};
        #pragma unroll
        for (int k2i = 0; k2i < 8; k2i++){
            uint4 q = wor[k2i];
            int k2l = kg*8 + k2i;
            uint32 y0 = yzP[0][k2l], y1 = yzP[1][k2l];
            uint32 y2 = yzP[2][k2l], y3 = yzP[3][k2l];
            a[0][0]=dot2h(y0,q.x,a[0][0]); a[0][1]=dot2h(y0,q.y,a[0][1]);
            a[0][2]=dot2h(y0,q.z,a[0][2]); a[0][3]=dot2h(y0,q.w,a[0][3]);
            a[1][0]=dot2h(y1,q.x,a[1][0]); a[1][1]=dot2h(y1,q.y,a[1][1]);
            a[1][2]=dot2h(y1,q.z,a[1][2]); a[1][3]=dot2h(y1,q.w,a[1][3]);
            a[2][0]=dot2h(y2,q.x,a[2][0]); a[2][1]=dot2h(y2,q.y,a[2][1]);
            a[2][2]=dot2h(y2,q.z,a[2][2]); a[2][3]=dot2h(y2,q.w,a[2][3]);
            a[3][0]=dot2h(y3,q.x,a[3][0]); a[3][1]=dot2h(y3,q.y,a[3][1]);
            a[3][2]=dot2h(y3,q.z,a[3][2]); a[3][3]=dot2h(y3,q.w,a[3][3]);
        }
        #pragma unroll
        for (int rr = 0; rr < 4; rr++)
            *(float4*)&red2[kg][rr][4*cq] = make_float4(a[rr][0],a[rr][1],a[rr][2],a[rr][3]);
    }
    __syncthreads();
    if (t < 512){
        int r2 = t >> 7, c4 = t & 127;
        float4 s = *(float4*)&red2[0][r2][4*c4];
        #pragma unroll
        for (int kk = 1; kk < 8; kk++){
            float4 q = *(float4*)&red2[kk][r2][4*c4];
            s.x += q.x; s.y += q.y; s.z += q.z; s.w += q.w;
        }
        *(float4*)&P.pP[((size_t)g*B + rg*4 + r2)*DM + 4*c4] = s;
    }
}

// per-agent head: fold(8 partials), LN, W_head GEMV, outputs, next x, zero partials
__global__ __launch_bounds__(512) void k_head(
    const float* __restrict__ xin, float* __restrict__ xout,
    float* __restrict__ pP,
    const float* __restrict__ lno, const float* __restrict__ Whead,
    const float* __restrict__ logstd, const float* __restrict__ eps,
    const float* __restrict__ Wemb, const float* __restrict__ bemb,
    float* __restrict__ out, int agent)
{
    int b = blockIdx.x, t = threadIdx.x, lane = t & 63, wid = t >> 6;
    __shared__ float ulnL[512];
    __shared__ float redH[512];
    __shared__ float wps[8], wpq[8], ms2[2];
    __shared__ float actv[AD], lpterm[AD];

    float v = xin[(size_t)b*DM + t];
    #pragma unroll
    for (int g = 0; g < 8; g++) v += pP[((size_t)g*B + b)*DM + t];
    float s = v, q = v*v;
    for (int off = 32; off > 0; off >>= 1){
        s += __shfl_down(s, off);
        q += __shfl_down(q, off);
    }
    if (lane == 0){ wps[wid] = s; wpq[wid] = q; }
    __syncthreads();
    if (t == 0){
        float S = 0.f, Q = 0.f;
        #pragma unroll
        for (int w2 = 0; w2 < 8; w2++){ S += wps[w2]; Q += wpq[w2]; }
        float m = S*(1.0f/DM);
        float var = Q*(1.0f/DM) - m*m;
        ms2[0] = m; ms2[1] = rsqrtf(var + 1e-5f);
    }
    __syncthreads();
    ulnL[t] = (v - ms2[0])*ms2[1]*lno[t];
    __syncthreads();
    {
        int ks = t >> 4, j = t & 15;
        float acc = 0.f;
        int k0 = ks*16;
        #pragma unroll
        for (int k = k0; k < k0 + 16; k++)
            acc += ulnL[k]*Whead[k*AD + j];
        redH[t] = acc;
    }
    __syncthreads();
    if (t < AD){
        int j = t;
        float mean = 0.f;
        #pragma unroll
        for (int ks = 0; ks < 32; ks++) mean += redH[ks*16 + j];
        float stdj = softplusf_(logstd[j]);
        float e = eps[((size_t)b*NA + agent)*AD + j];
        float raw = mean + stdj*e;
        float act = tanhf(raw);
        out[((size_t)b*NA + agent)*AD + j] = act;                                    // acts
        out[(size_t)NA*B*AD + (size_t)B*NA + ((size_t)b*NA + agent)*AD + j] = raw;   // raws
        actv[j] = act;
        lpterm[j] = -0.5f*e*e - logf(stdj)
                    - 2.0f*(0.69314718f - raw - softplusf_(-2.0f*raw));
    }
    __syncthreads();
    if (t == 0){
        float lp = 0.f;
        #pragma unroll
        for (int j = 0; j < AD; j++) lp += lpterm[j];
        lp -= 0.5f*AD*1.8378770664f;
        out[(size_t)NA*B*AD + (size_t)b*NA + agent] = lp;                            // logs
    }
    float v2 = bemb[t];
    #pragma unroll
    for (int j = 0; j < AD; j++)
        v2 += actv[j]*Wemb[j*DM + t];
    xout[(size_t)b*DM + t] = v2;
    #pragma unroll
    for (int g = 0; g < 8; g++) pP[((size_t)g*B + b)*DM + t] = 0.f;
}

// ---------------- launch ----------------

extern "C" void kernel_launch(void* const* d_in, const int* in_sizes, int n_in,
                              void* d_out, int out_size, void* d_ws, size_t ws_size,
                              hipStream_t stream)
{
    const float* in[29];
    for (int k = 0; k < 29; k++) in[k] = (const float*)d_in[k];

    // workspace layout (bytes) — same as round 7 (~110 MB of 256 MB)
    char* wsb = (char*)d_ws;
    uint32* W1H  = (uint32*)(wsb + 0);           // 16,777,216  [8][256][2048]
    uint32* WoH  = (uint32*)(wsb + 16777216);    //  8,388,608  [8][512][512]
    uint32* WxH  = (uint32*)(wsb + 25165824);    //  1,572,864  [8][96][512]
    uint32* WdtH = (uint32*)(wsb + 26738688);    //    524,288  [8][16][1024]
    float*  negA = (float*) (wsb + 27262976);    //  1,048,576
    float*  ctx  = (float*) (wsb + 28311552);    //  2,097,152
    float*  xb0  = (float*) (wsb + 30408704);    //    262,144
    float*  xb1  = (float*) (wsb + 30670848);    //    262,144
    float*  xcG  = (float*) (wsb + 30932992);    //    524,288
    float*  szG  = (float*) (wsb + 31457280);    //    524,288
    float*  xpP  = (float*) (wsb + 31981568);    //    262,144 (uses 196,608)
    float*  pP   = (float*) (wsb + 32243712);    //  2,097,152  [8][B][DM]
    uint32* convrU = (uint32*)(wsb + 34340864);  //  8,388,608  f16-pair ring
    uint32* hG   = (uint32*)(wsb + 42729472);    // 67,108,864  [bs][row][qq][d] f16 uint4

    float* out = (float*)d_out;
    float* xb[2] = {xb0, xb1};

    k_setup<<<dim3(29696), 256, 0, stream>>>(
        in[11], in[20], in[19], in[28], in[14], in[23], in[15], in[24],
        in[17], in[26], in[4], W1H, WoH, WxH, WdtH, negA, xb0, pP);
    k_ctx<<<dim3(B*NA), 256, 0, stream>>>(in[0], in[1], in[5], ctx);

    SP P;
    P.W1H = W1H; P.WoH = WoH; P.WxH = WxH; P.WdtH = WdtH;
    P.negA = negA; P.ctxG = ctx;
    P.cw_s = in[12]; P.cb_s = in[13]; P.dtb_s = in[16]; P.D_s = in[18];
    P.cw_c = in[21]; P.cb_c = in[22]; P.dtb_c = in[25]; P.D_c = in[27];
    P.ln1 = in[6]; P.ln2 = in[7];
    P.xcG = xcG; P.szG = szG; P.xpP = xpP; P.pP = pP;
    P.convrU = convrU; P.hG = hG;

    int cur = 0;
    for (int i = 0; i < NA; i++){
        for (int bs = 0; bs < 8; bs++){
            k_step1<<<dim3(256), 1024, 0, stream>>>(P, xb[cur], xb[cur^1], i, bs);
            cur ^= 1;
            k_step2<<<dim3(256), 1024, 0, stream>>>(P, i, bs);
        }
        k_head<<<dim3(B), 512, 0, stream>>>(xb[cur], xb[cur^1], pP,
                in[8], in[9], in[10], in[2], in[3], in[4], out, i);
        cur ^= 1;
    }
}

// Round 9
// 1940.080 us; speedup vs baseline: 1.0418x; 1.0418x over previous
//
#include <hip/hip_runtime.h>
#include <hip/hip_bf16.h>

#define B   128
#define NA  8
#define AD  16
#define DM  512
#define DI  1024
#define DS  32
#define DC  4
#define DR  32
#define NB  4
#define OD  128

typedef unsigned int uint32;
typedef _Float16 h2f __attribute__((ext_vector_type(2)));

__device__ __forceinline__ float sigmoidf_(float x){ return 1.0f/(1.0f+__expf(-x)); }
__device__ __forceinline__ float softplusf_(float x){ return fmaxf(x,0.0f)+log1pf(__expf(-fabsf(x))); }

// f16 pair helpers: one uint32 = half2 (lo = first, hi = second)
__device__ __forceinline__ float dot2h(uint32 a, uint32 b, float c){
    union { uint32 u; h2f h; } ua, ub;
    ua.u = a; ub.u = b;
#if __has_builtin(__builtin_amdgcn_fdot2)
    return __builtin_amdgcn_fdot2(ua.h, ub.h, c, false);
#else
    return c + (float)ua.h.x*(float)ub.h.x + (float)ua.h.y*(float)ub.h.y;
#endif
}
__device__ __forceinline__ uint32 packh2(float a, float b){
    union { uint32 u; h2f h; } w;
    w.h.x = (_Float16)a; w.h.y = (_Float16)b;
    return w.u;
}
__device__ __forceinline__ float loh(uint32 u){
    union { uint32 uu; h2f h; } w; w.uu = u; return (float)w.h.x;
}
__device__ __forceinline__ float hih(uint32 u){
    union { uint32 uu; h2f h; } w; w.uu = u; return (float)w.h.y;
}

// ---------------- init / conversion kernels ----------------

__global__ __launch_bounds__(256) void k_ctx(const float* __restrict__ obs_rep,
    const float* __restrict__ obs, const float* __restrict__ Wobs,
    float* __restrict__ ctx)
{
    int ib = blockIdx.x;          // < B*8
    int b = ib >> 3, i = ib & 7;
    __shared__ float orow[OD];
    int tid = threadIdx.x;
    if (tid < OD) orow[tid] = obs[(size_t)(b*NA+i)*OD + tid];
    __syncthreads();
    for (int m = tid; m < DM; m += 256){
        float acc = obs_rep[(size_t)(b*NA+i)*DM + m];
        for (int o = 0; o < OD; o++)
            acc += orow[o]*Wobs[o*DM + m];
        ctx[(size_t)(i*B + b)*DM + m] = acc;
    }
}

// merged converter: W1H | WoH | WxH | WdtH | negA | pP/xb0  (index-ranged)
__global__ __launch_bounds__(256) void k_setup(
    const float* __restrict__ W1s, const float* __restrict__ W1c,
    const float* __restrict__ Wos, const float* __restrict__ Woc,
    const float* __restrict__ Wxs, const float* __restrict__ Wxc,
    const float* __restrict__ Wds, const float* __restrict__ Wdc,
    const float* __restrict__ Als, const float* __restrict__ Alc,
    const float* __restrict__ bemb,
    uint32* __restrict__ W1H, uint32* __restrict__ WoH,
    uint32* __restrict__ WxH, uint32* __restrict__ WdtH,
    float* __restrict__ negA, float* __restrict__ xb0, float* __restrict__ pP)
{
    int idx = blockIdx.x*256 + threadIdx.x;
    if (idx < 4194304){   // W1H [8][256][2048]
        int bs = idx >> 19, rr = idx & 524287;
        int k2 = rr >> 11, c = rr & 2047;
        int nb = bs >> 1, st = bs & 1;
        const float* src = (st ? W1c : W1s) + (size_t)nb*1048576 + (size_t)(2*k2)*2048 + c;
        W1H[idx] = packh2(src[0], src[2048]);
        return;
    }
    idx -= 4194304;
    if (idx < 2097152){   // WoH [8][512][512]
        int bs = idx >> 18, rr = idx & 262143;
        int k2 = rr >> 9, c = rr & 511;
        int nb = bs >> 1, st = bs & 1;
        const float* src = (st ? Woc : Wos) + (size_t)nb*DI*DM + (size_t)(2*k2)*DM + c;
        WoH[idx] = packh2(src[0], src[DM]);
        return;
    }
    idx -= 2097152;
    if (idx < 393216){    // WxH [8][96][512]
        int bs = idx / 49152, rr = idx % 49152;
        int j = rr >> 9, k2 = rr & 511;
        int nb = bs >> 1, st = bs & 1;
        const float* src = (st ? Wxc : Wxs) + (size_t)nb*DI*96 + (size_t)(2*k2)*96 + j;
        WxH[idx] = packh2(src[0], src[96]);
        return;
    }
    idx -= 393216;
    if (idx < 131072){    // WdtH [8][16][1024]
        int bs = idx >> 14, rr = idx & 16383;
        int r2 = rr >> 10, d = rr & 1023;
        int nb = bs >> 1, st = bs & 1;
        const float* src = (st ? Wdc : Wds) + (size_t)nb*DR*DI + (size_t)(2*r2)*DI + d;
        WdtH[idx] = packh2(src[0], src[DI]);
        return;
    }
    idx -= 131072;
    if (idx < 262144){    // negA
        int bs = idx >> 15, rr = idx & 32767;
        int nb = bs >> 1, st = bs & 1;
        const float* src = (st ? Alc : Als) + (size_t)nb*DI*DS + rr;
        negA[idx] = -__expf(*src);
        return;
    }
    idx -= 262144;
    // idx < 524288: pP zero; first 65536 also xb0 init
    pP[idx] = 0.f;
    if (idx < B*DM) xb0[idx] = bemb[idx & (DM-1)];
}

// ---------------- per-step kernels (round-7 proven bodies) ----------------

struct SP {
    const uint32 *W1H, *WoH, *WxH, *WdtH;
    const float *negA, *ctxG;
    const float *cw_s, *cb_s, *dtb_s, *D_s;
    const float *cw_c, *cb_c, *dtb_c, *D_c;
    const float *ln1, *ln2;
    float *xcG, *szG, *xpP, *pP;
    uint32 *convrU, *hG;
};

// grid 256 = 32 rowgroups (R=4 rows) x 8 colgroups, 1024 threads.
// gemm1 weights: one thread loads a uint4 once (in-loop; compiler schedules)
// and applies it to all 4 rows (16 dot2 / 16B load).
__global__ __launch_bounds__(1024) void k_step1(SP P, const float* __restrict__ xin,
    float* __restrict__ xout, int i, int bs)
{
    int rg = blockIdx.x >> 3, cg = blockIdx.x & 7;
    int t = threadIdx.x;
    int st = bs & 1, nb = bs >> 1;
    const float* lns = (st ? P.ln2 : P.ln1) + (size_t)nb*DM;
    const float* cw  = (st ? P.cw_c : P.cw_s) + (size_t)nb*DC*DI;
    const float* cb  = (st ? P.cb_c : P.cb_s) + (size_t)nb*DI;

    __shared__ uint32 ulnP[4][256];
    __shared__ float red1[16][4][256];   // 64 KB
    __shared__ float xzL[4][256];
    __shared__ uint32 xcP[4][128];
    __shared__ float wred[4][2][2];
    __shared__ float ms2[4][2];

    // ---- fold x + sum(pP) (t<512: row r of 4, 4 consecutive cols) ----
    int r = (t >> 7) & 3, cq = t & 127;
    float4 v4 = make_float4(0.f,0.f,0.f,0.f);
    if (t < 512){
        int row = rg*4 + r;
        v4 = *(const float4*)&xin[(size_t)row*DM + cq*4];
        #pragma unroll
        for (int gg = 0; gg < 8; gg++){
            float4 q4 = *(const float4*)&P.pP[((size_t)gg*B + row)*DM + cq*4];
            v4.x += q4.x; v4.y += q4.y; v4.z += q4.z; v4.w += q4.w;
        }
        if (cg == 0) *(float4*)&xout[(size_t)row*DM + cq*4] = v4;
        float sv = v4.x+v4.y+v4.z+v4.w;
        float qv = v4.x*v4.x+v4.y*v4.y+v4.z*v4.z+v4.w*v4.w;
        #pragma unroll
        for (int off = 32; off > 0; off >>= 1){
            sv += __shfl_down(sv, off);
            qv += __shfl_down(qv, off);
        }
        int lane = t & 63, wid = t >> 6;
        if (lane == 0){ wred[wid>>1][wid&1][0] = sv; wred[wid>>1][wid&1][1] = qv; }
    }
    __syncthreads();
    if (t < 4){
        float S = wred[t][0][0] + wred[t][1][0];
        float Q = wred[t][0][1] + wred[t][1][1];
        float m = S*(1.0f/DM);
        float var = Q*(1.0f/DM) - m*m;
        ms2[t][0] = m; ms2[t][1] = rsqrtf(var + 1e-5f);
    }
    __syncthreads();

    // ---- LN -> packed f16 pairs ----
    if (t < 512){
        int row = rg*4 + r;
        float m = ms2[r][0], rs = ms2[r][1];
        float4 l4 = *(const float4*)&lns[cq*4];
        float u0 = (v4.x - m)*rs*l4.x;
        float u1 = (v4.y - m)*rs*l4.y;
        float u2 = (v4.z - m)*rs*l4.z;
        float u3 = (v4.w - m)*rs*l4.w;
        if (st){
            float4 c4 = *(const float4*)&P.ctxG[((size_t)i*B + row)*DM + cq*4];
            u0 += c4.x; u1 += c4.y; u2 += c4.z; u3 += c4.w;
        }
        ulnP[r][2*cq]   = packh2(u0, u1);
        ulnP[r][2*cq+1] = packh2(u2, u3);
    }
    __syncthreads();

    // ---- gemm1: thread = (colquad cp of 64, k2-chunk kg of 16x16); 4 rows each ----
    {
        int cp = t & 63, kg = t >> 6;
        const uint32* w1 = P.W1H + ((size_t)bs << 19);     // [256 k2][2048 c]
        int k2b = kg*16;
        const uint4* wp = (const uint4*)(w1 + ((size_t)k2b << 11)) + (cg*64 + cp);
        float a[4][4] = {};
        #pragma unroll 4
        for (int k2i = 0; k2i < 16; k2i++){
            uint4 q = wp[(size_t)k2i << 9];
            int k2 = k2b + k2i;
            uint32 u0 = ulnP[0][k2], u1 = ulnP[1][k2];
            uint32 u2 = ulnP[2][k2], u3 = ulnP[3][k2];
            a[0][0]=dot2h(u0,q.x,a[0][0]); a[0][1]=dot2h(u0,q.y,a[0][1]);
            a[0][2]=dot2h(u0,q.z,a[0][2]); a[0][3]=dot2h(u0,q.w,a[0][3]);
            a[1][0]=dot2h(u1,q.x,a[1][0]); a[1][1]=dot2h(u1,q.y,a[1][1]);
            a[1][2]=dot2h(u1,q.z,a[1][2]); a[1][3]=dot2h(u1,q.w,a[1][3]);
            a[2][0]=dot2h(u2,q.x,a[2][0]); a[2][1]=dot2h(u2,q.y,a[2][1]);
            a[2][2]=dot2h(u2,q.z,a[2][2]); a[2][3]=dot2h(u2,q.w,a[2][3]);
            a[3][0]=dot2h(u3,q.x,a[3][0]); a[3][1]=dot2h(u3,q.y,a[3][1]);
            a[3][2]=dot2h(u3,q.z,a[3][2]); a[3][3]=dot2h(u3,q.w,a[3][3]);
        }
        #pragma unroll
        for (int rr = 0; rr < 4; rr++)
            *(float4*)&red1[kg][rr][4*cp] = make_float4(a[rr][0],a[rr][1],a[rr][2],a[rr][3]);
    }
    __syncthreads();
    {
        int r2 = t >> 8, c = t & 255;
        float sacc = red1[0][r2][c];
        #pragma unroll
        for (int gk = 1; gk < 16; gk++) sacc += red1[gk][r2][c];
        xzL[r2][c] = sacc;
    }
    __syncthreads();

    if (cg < 4){
        // ---- conv ring + silu -> xc (t<512) ----
        if (t < 512){
            int r3 = r, pi = cq;
            int row3 = rg*4 + r3;
            int d0 = cg*256 + 2*pi;
            float xz0 = xzL[r3][2*pi], xz1 = xzL[r3][2*pi+1];
            uint32* ring = P.convrU + ((size_t)bs << 18);   // [4][128][512] f16 pairs
            size_t rb = (size_t)row3*512 + (d0>>1);
            ring[((size_t)(i&3))*65536 + rb] = packh2(xz0, xz1);
            float s0 = cb[d0]   + cw[3*DI + d0]  *xz0;
            float s1 = cb[d0+1] + cw[3*DI + d0+1]*xz1;
            if (i >= 1){ uint32 uu = ring[((size_t)((i-1)&3))*65536 + rb];
                s0 += cw[2*DI + d0]*loh(uu); s1 += cw[2*DI + d0+1]*hih(uu); }
            if (i >= 2){ uint32 uu = ring[((size_t)((i-2)&3))*65536 + rb];
                s0 += cw[1*DI + d0]*loh(uu); s1 += cw[1*DI + d0+1]*hih(uu); }
            if (i >= 3){ uint32 uu = ring[((size_t)((i-3)&3))*65536 + rb];
                s0 += cw[0*DI + d0]*loh(uu); s1 += cw[0*DI + d0+1]*hih(uu); }
            float xc0 = s0*sigmoidf_(s0), xc1 = s1*sigmoidf_(s1);
            P.xcG[(size_t)row3*DI + d0]   = xc0;
            P.xcG[(size_t)row3*DI + d0+1] = xc1;
            xcP[r3][pi] = packh2(xc0, xc1);
        }
        __syncthreads();
        // ---- xproj partial over this 256-k slice (128 k2, dot2) ----
        if (t < 384){
            int rx = t/96, j = t - rx*96;
            const uint4* wx = (const uint4*)(P.WxH + (size_t)bs*49152
                                             + ((size_t)j << 9) + (cg << 7));
            const uint32* xr = xcP[rx];
            float acc = 0.f;
            #pragma unroll 8
            for (int ii = 0; ii < 32; ii++){
                uint4 q = wx[ii];
                acc = dot2h(xr[4*ii+0], q.x, acc);
                acc = dot2h(xr[4*ii+1], q.y, acc);
                acc = dot2h(xr[4*ii+2], q.z, acc);
                acc = dot2h(xr[4*ii+3], q.w, acc);
            }
            P.xpP[((size_t)cg*B + rg*4 + rx)*96 + j] = acc;
        }
    } else {
        // ---- z path: sz ----
        int r2 = t >> 8, c = t & 255;
        int row2 = rg*4 + r2;
        int d = (cg-4)*256 + c;
        float xz = xzL[r2][c];
        P.szG[(size_t)row2*DI + d] = xz*sigmoidf_(xz);
    }
}

// step2: rowS fold, dt (dot2), scan + y, gemm2 (thread loads weight uint4 once,
// applies to 4 rows: 8 loads / 128 dot2) -> pP[g]
__global__ __launch_bounds__(1024) void k_step2(SP P, int i, int bs)
{
    int rg = blockIdx.x >> 3, g = blockIdx.x & 7;
    int t = threadIdx.x;
    int st = bs & 1, nb = bs >> 1;
    const float* dtbp = (st ? P.dtb_c : P.dtb_s) + (size_t)nb*DI;
    const float* Dpp  = (st ? P.D_c   : P.D_s  ) + (size_t)nb*DI;
    const int first = (i == 0);

    __shared__ float rowS[4][96];
    __shared__ uint32 rowSP[4][16];
    __shared__ float yzL[4][128];
    __shared__ uint32 yzP[4][64];
    __shared__ float red2[8][4][624];   // padded cols: ~80 KB -> 1 block/CU

    if (t < 384){
        int rx = t/96, j = t - rx*96;
        int row0 = rg*4 + rx;
        size_t base = (size_t)row0*96 + j;
        rowS[rx][j] = P.xpP[base] + P.xpP[(size_t)B*96 + base]
                    + P.xpP[(size_t)2*B*96 + base] + P.xpP[(size_t)3*B*96 + base];
    }
    __syncthreads();
    if (t < 64){
        int rx = t >> 4, q = t & 15;
        rowSP[rx][q] = packh2(rowS[rx][2*q], rowS[rx][2*q+1]);
    }
    __syncthreads();

    if (t < 512){
        int r = t >> 7, dl = t & 127;
        int d = g*128 + dl;
        int row = rg*4 + r;
        float dp = dtbp[d];
        const uint32* wdt = P.WdtH + ((size_t)bs << 14) + d;   // [16 r2][1024 d]
        #pragma unroll
        for (int r2 = 0; r2 < 16; r2++)
            dp = dot2h(rowSP[r][r2], wdt[(size_t)r2 << 10], dp);
        float delta = softplusf_(dp);
        float xcv = P.xcG[(size_t)row*DI + d];
        float dxc = delta*xcv;
        const float4* nap = (const float4*)(P.negA + ((size_t)bs << 15) + (size_t)d*DS);
        uint4* hb = ((uint4*)P.hG) + ((size_t)(bs*B + row) << 12) + d;  // [qq][1024]
        float y = 0.f;
        #pragma unroll
        for (int qq = 0; qq < 4; qq++){
            uint4 hu = first ? make_uint4(0u,0u,0u,0u) : hb[qq << 10];
            float4 na0 = nap[2*qq], na1 = nap[2*qq+1];
            int s0 = 8*qq;
            float h0 = loh(hu.x), h1 = hih(hu.x);
            float h2 = loh(hu.y), h3 = hih(hu.y);
            float h4 = loh(hu.z), h5 = hih(hu.z);
            float h6 = loh(hu.w), h7 = hih(hu.w);
            h0 = __expf(delta*na0.x)*h0 + dxc*rowS[r][DR+s0+0];
            h1 = __expf(delta*na0.y)*h1 + dxc*rowS[r][DR+s0+1];
            h2 = __expf(delta*na0.z)*h2 + dxc*rowS[r][DR+s0+2];
            h3 = __expf(delta*na0.w)*h3 + dxc*rowS[r][DR+s0+3];
            h4 = __expf(delta*na1.x)*h4 + dxc*rowS[r][DR+s0+4];
            h5 = __expf(delta*na1.y)*h5 + dxc*rowS[r][DR+s0+5];
            h6 = __expf(delta*na1.z)*h6 + dxc*rowS[r][DR+s0+6];
            h7 = __expf(delta*na1.w)*h7 + dxc*rowS[r][DR+s0+7];
            y += h0*rowS[r][DR+DS+s0+0] + h1*rowS[r][DR+DS+s0+1]
               + h2*rowS[r][DR+DS+s0+2] + h3*rowS[r][DR+DS+s0+3]
               + h4*rowS[r][DR+DS+s0+4] + h5*rowS[r][DR+DS+s0+5]
               + h6*rowS[r][DR+DS+s0+6] + h7*rowS[r][DR+DS+s0+7];
            hu.x = packh2(h0,h1); hu.y = packh2(h2,h3);
            hu.z = packh2(h4,h5); hu.w = packh2(h6,h7);
            hb[qq << 10] = hu;
        }
        y += Dpp[d]*xcv;
        yzL[r][dl] = y*P.szG[(size_t)row*DI + d];
    }
    __syncthreads();
    if (t < 256){
        int rr = t >> 6, k2 = t & 63;
        yzP[rr][k2] = packh2(yzL[rr][2*k2], yzL[rr][2*k2+1]);
    }
    __syncthreads();

    // gemm2: thread = (colquad cq of 128, k2-chunk kg of 8x8); 4 rows each
    {
        int cq = t & 127, kg = t >> 7;
        const uint32* wo = P.WoH + ((size_t)bs << 18);      // [512 k2][512 c]
        int k2b = g*64 + kg*8;
        const uint4* wp = (const uint4*)(wo + ((size_t)k2b << 9)) + cq;
        float a[4][4] = {};
        #pragma unroll
        for (int k2i = 0; k2i < 8; k2i++){
            uint4 q = wp[(size_t)k2i << 7];
            int k2l = kg*8 + k2i;
            uint32 y0 = yzP[0][k2l], y1 = yzP[1][k2l];
            uint32 y2 = yzP[2][k2l], y3 = yzP[3][k2l];
            a[0][0]=dot2h(y0,q.x,a[0][0]); a[0][1]=dot2h(y0,q.y,a[0][1]);
            a[0][2]=dot2h(y0,q.z,a[0][2]); a[0][3]=dot2h(y0,q.w,a[0][3]);
            a[1][0]=dot2h(y1,q.x,a[1][0]); a[1][1]=dot2h(y1,q.y,a[1][1]);
            a[1][2]=dot2h(y1,q.z,a[1][2]); a[1][3]=dot2h(y1,q.w,a[1][3]);
            a[2][0]=dot2h(y2,q.x,a[2][0]); a[2][1]=dot2h(y2,q.y,a[2][1]);
            a[2][2]=dot2h(y2,q.z,a[2][2]); a[2][3]=dot2h(y2,q.w,a[2][3]);
            a[3][0]=dot2h(y3,q.x,a[3][0]); a[3][1]=dot2h(y3,q.y,a[3][1]);
            a[3][2]=dot2h(y3,q.z,a[3][2]); a[3][3]=dot2h(y3,q.w,a[3][3]);
        }
        #pragma unroll
        for (int rr = 0; rr < 4; rr++)
            *(float4*)&red2[kg][rr][4*cq] = make_float4(a[rr][0],a[rr][1],a[rr][2],a[rr][3]);
    }
    __syncthreads();
    if (t < 512){
        int r2 = t >> 7, c4 = t & 127;
        float4 s = *(float4*)&red2[0][r2][4*c4];
        #pragma unroll
        for (int kg = 1; kg < 8; kg++){
            float4 q = *(float4*)&red2[kg][r2][4*c4];
            s.x += q.x; s.y += q.y; s.z += q.z; s.w += q.w;
        }
        *(float4*)&P.pP[((size_t)g*B + rg*4 + r2)*DM + 4*c4] = s;
    }
}

// per-agent head: fold(8 partials), LN, W_head GEMV, outputs, next x, zero partials
__global__ __launch_bounds__(512) void k_head(
    const float* __restrict__ xin, float* __restrict__ xout,
    float* __restrict__ pP,
    const float* __restrict__ lno, const float* __restrict__ Whead,
    const float* __restrict__ logstd, const float* __restrict__ eps,
    const float* __restrict__ Wemb, const float* __restrict__ bemb,
    float* __restrict__ out, int agent)
{
    int b = blockIdx.x, t = threadIdx.x, lane = t & 63, wid = t >> 6;
    __shared__ float ulnL[512];
    __shared__ float redH[512];
    __shared__ float wps[8], wpq[8], ms2[2];
    __shared__ float actv[AD], lpterm[AD];

    float v = xin[(size_t)b*DM + t];
    #pragma unroll
    for (int g = 0; g < 8; g++) v += pP[((size_t)g*B + b)*DM + t];
    float s = v, q = v*v;
    for (int off = 32; off > 0; off >>= 1){
        s += __shfl_down(s, off);
        q += __shfl_down(q, off);
    }
    if (lane == 0){ wps[wid] = s; wpq[wid] = q; }
    __syncthreads();
    if (t == 0){
        float S = 0.f, Q = 0.f;
        #pragma unroll
        for (int w2 = 0; w2 < 8; w2++){ S += wps[w2]; Q += wpq[w2]; }
        float m = S*(1.0f/DM);
        float var = Q*(1.0f/DM) - m*m;
        ms2[0] = m; ms2[1] = rsqrtf(var + 1e-5f);
    }
    __syncthreads();
    ulnL[t] = (v - ms2[0])*ms2[1]*lno[t];
    __syncthreads();
    {
        int ks = t >> 4, j = t & 15;
        float acc = 0.f;
        int k0 = ks*16;
        #pragma unroll
        for (int k = k0; k < k0 + 16; k++)
            acc += ulnL[k]*Whead[k*AD + j];
        redH[t] = acc;
    }
    __syncthreads();
    if (t < AD){
        int j = t;
        float mean = 0.f;
        #pragma unroll
        for (int ks = 0; ks < 32; ks++) mean += redH[ks*16 + j];
        float stdj = softplusf_(logstd[j]);
        float e = eps[((size_t)b*NA + agent)*AD + j];
        float raw = mean + stdj*e;
        float act = tanhf(raw);
        out[((size_t)b*NA + agent)*AD + j] = act;                                    // acts
        out[(size_t)NA*B*AD + (size_t)B*NA + ((size_t)b*NA + agent)*AD + j] = raw;   // raws
        actv[j] = act;
        lpterm[j] = -0.5f*e*e - logf(stdj)
                    - 2.0f*(0.69314718f - raw - softplusf_(-2.0f*raw));
    }
    __syncthreads();
    if (t == 0){
        float lp = 0.f;
        #pragma unroll
        for (int j = 0; j < AD; j++) lp += lpterm[j];
        lp -= 0.5f*AD*1.8378770664f;
        out[(size_t)NA*B*AD + (size_t)b*NA + agent] = lp;                            // logs
    }
    float v2 = bemb[t];
    #pragma unroll
    for (int j = 0; j < AD; j++)
        v2 += actv[j]*Wemb[j*DM + t];
    xout[(size_t)b*DM + t] = v2;
    #pragma unroll
    for (int g = 0; g < 8; g++) pP[((size_t)g*B + b)*DM + t] = 0.f;
}

// ---------------- launch ----------------

extern "C" void kernel_launch(void* const* d_in, const int* in_sizes, int n_in,
                              void* d_out, int out_size, void* d_ws, size_t ws_size,
                              hipStream_t stream)
{
    const float* in[29];
    for (int k = 0; k < 29; k++) in[k] = (const float*)d_in[k];

    // workspace layout (bytes) — same as round 7 (~110 MB of 256 MB)
    char* wsb = (char*)d_ws;
    uint32* W1H  = (uint32*)(wsb + 0);           // 16,777,216  [8][256][2048]
    uint32* WoH  = (uint32*)(wsb + 16777216);    //  8,388,608  [8][512][512]
    uint32* WxH  = (uint32*)(wsb + 25165824);    //  1,572,864  [8][96][512]
    uint32* WdtH = (uint32*)(wsb + 26738688);    //    524,288  [8][16][1024]
    float*  negA = (float*) (wsb + 27262976);    //  1,048,576
    float*  ctx  = (float*) (wsb + 28311552);    //  2,097,152
    float*  xb0  = (float*) (wsb + 30408704);    //    262,144
    float*  xb1  = (float*) (wsb + 30670848);    //    262,144
    float*  xcG  = (float*) (wsb + 30932992);    //    524,288
    float*  szG  = (float*) (wsb + 31457280);    //    524,288
    float*  xpP  = (float*) (wsb + 31981568);    //    262,144 (uses 196,608)
    float*  pP   = (float*) (wsb + 32243712);    //  2,097,152  [8][B][DM]
    uint32* convrU = (uint32*)(wsb + 34340864);  //  8,388,608  f16-pair ring
    uint32* hG   = (uint32*)(wsb + 42729472);    // 67,108,864  [bs][row][qq][d] f16 uint4

    float* out = (float*)d_out;
    float* xb[2] = {xb0, xb1};

    k_setup<<<dim3(29696), 256, 0, stream>>>(
        in[11], in[20], in[19], in[28], in[14], in[23], in[15], in[24],
        in[17], in[26], in[4], W1H, WoH, WxH, WdtH, negA, xb0, pP);
    k_ctx<<<dim3(B*NA), 256, 0, stream>>>(in[0], in[1], in[5], ctx);

    SP P;
    P.W1H = W1H; P.WoH = WoH; P.WxH = WxH; P.WdtH = WdtH;
    P.negA = negA; P.ctxG = ctx;
    P.cw_s = in[12]; P.cb_s = in[13]; P.dtb_s = in[16]; P.D_s = in[18];
    P.cw_c = in[21]; P.cb_c = in[22]; P.dtb_c = in[25]; P.D_c = in[27];
    P.ln1 = in[6]; P.ln2 = in[7];
    P.xcG = xcG; P.szG = szG; P.xpP = xpP; P.pP = pP;
    P.convrU = convrU; P.hG = hG;

    int cur = 0;
    for (int i = 0; i < NA; i++){
        for (int bs = 0; bs < 8; bs++){
            k_step1<<<dim3(256), 1024, 0, stream>>>(P, xb[cur], xb[cur^1], i, bs);
            cur ^= 1;
            k_step2<<<dim3(256), 1024, 0, stream>>>(P, i, bs);
        }
        k_head<<<dim3(B), 512, 0, stream>>>(xb[cur], xb[cur^1], pP,
                in[8], in[9], in[10], in[2], in[3], in[4], out, i);
        cur ^= 1;
    }
}